// Round 2
// baseline (1311.427 us; speedup 1.0000x reference)
//
#include <hip/hip_runtime.h>
#include <hip/hip_bf16.h>
#include <math.h>

typedef __attribute__((ext_vector_type(8))) __bf16 bf16x8;
typedef __attribute__((ext_vector_type(4))) float floatx4;

__device__ inline unsigned short f2u(float f) {
  __hip_bfloat16 h = __float2bfloat16(f);
  unsigned short u;
  __builtin_memcpy(&u, &h, 2);
  return u;
}

__device__ inline floatx4 mfma16(bf16x8 a, bf16x8 b, floatx4 c) {
  return __builtin_amdgcn_mfma_f32_16x16x32_bf16(a, b, c, 0, 0, 0);
}

__device__ inline void gload_lds16(const unsigned short* g, unsigned short* l) {
  __builtin_amdgcn_global_load_lds(
      (__attribute__((address_space(1))) void*)g,
      (__attribute__((address_space(3))) void*)l,
      16, 0, 0);
}

// ---------------- cast fp32 -> bf16 (vectorized, optional scale) ----------------
__global__ __launch_bounds__(256) void castk(const float* __restrict__ in,
                                             unsigned short* __restrict__ out,
                                             int n4, float scale) {
  int i = blockIdx.x * 256 + threadIdx.x;
  if (i >= n4) return;
  const float4 v = reinterpret_cast<const float4*>(in)[i];
  ushort4 o;
  o.x = f2u(v.x * scale);
  o.y = f2u(v.y * scale);
  o.z = f2u(v.z * scale);
  o.w = f2u(v.w * scale);
  reinterpret_cast<ushort4*>(out)[i] = o;
}

// ---------------- GEMM: C[m,n] = sum_k A[m,k] * B[n,k]  (both row-major, K inner) ----
// 128x128 tile, BK=32, 4 waves (2x2), 4x4 16x16x32 bf16 MFMA frags per wave.
// OUT: 0 = bf16 row-major, 1 = f32 row-major + bias, 2 = bf16 transposed-per-head
//      (Vtg[((b*16+hv)*128+dh)*2048 + t], for the V projection)
template <int OUT>
__global__ __launch_bounds__(256)
void gemm_bt(const unsigned short* __restrict__ A,
             const unsigned short* __restrict__ B,
             unsigned short* __restrict__ Cb,
             float* __restrict__ Cf,
             const float* __restrict__ bias,
             int M, int N, int K) {
  __shared__ unsigned short Asm_[128 * 32];
  __shared__ unsigned short Bsm_[128 * 32];
  const int t = threadIdx.x;
  const int w = t >> 6;
  const int l = t & 63;
  const int m0 = blockIdx.y * 128;
  const int n0 = blockIdx.x * 128;
  const int wm = w >> 1, wn = w & 1;

  const int srow = l >> 2;
  const int scol = (l & 3) * 8;
  const unsigned short* gA = A + (size_t)(m0 + w * 32 + srow) * K + scol;
  const unsigned short* gB = B + (size_t)(n0 + w * 32 + srow) * K + scol;
  unsigned short* lA = &Asm_[w * 1024];
  unsigned short* lB = &Bsm_[w * 1024];

  floatx4 acc[4][4];
#pragma unroll
  for (int i = 0; i < 4; i++)
#pragma unroll
    for (int j = 0; j < 4; j++) acc[i][j] = (floatx4){0.f, 0.f, 0.f, 0.f};

  const int fr = l & 15;
  const int fk = (l >> 4) * 8;

  for (int k0 = 0; k0 < K; k0 += 32) {
    gload_lds16(gA + k0, lA);
    gload_lds16(gA + (size_t)16 * K + k0, lA + 512);
    gload_lds16(gB + k0, lB);
    gload_lds16(gB + (size_t)16 * K + k0, lB + 512);
    __syncthreads();

    bf16x8 af[4], bfr[4];
#pragma unroll
    for (int i = 0; i < 4; i++)
      af[i] = *reinterpret_cast<const bf16x8*>(&Asm_[(wm * 64 + i * 16 + fr) * 32 + fk]);
#pragma unroll
    for (int j = 0; j < 4; j++)
      bfr[j] = *reinterpret_cast<const bf16x8*>(&Bsm_[(wn * 64 + j * 16 + fr) * 32 + fk]);
#pragma unroll
    for (int i = 0; i < 4; i++)
#pragma unroll
      for (int j = 0; j < 4; j++) acc[i][j] = mfma16(af[i], bfr[j], acc[i][j]);
    __syncthreads();
  }

  const int er = (l >> 4) * 4;
  const int ec = l & 15;
#pragma unroll
  for (int i = 0; i < 4; i++) {
#pragma unroll
    for (int j = 0; j < 4; j++) {
      const int col = n0 + wn * 64 + j * 16 + ec;
      if (OUT == 2) {
        // transposed V write: row = b*2048 + t, col = hv*128 + dh
        const int hv = col >> 7, dh = col & 127;
        const int row0 = m0 + wm * 64 + i * 16 + er;
        const int bb = row0 >> 11;
        const int t0 = row0 & 2047;
        unsigned short* vp =
            Cb + (((size_t)(bb * 16 + hv)) * 128 + dh) * 2048 + t0;
#pragma unroll
        for (int r = 0; r < 4; r++) vp[r] = f2u(acc[i][j][r]);
      } else {
#pragma unroll
        for (int r = 0; r < 4; r++) {
          const int row = m0 + wm * 64 + i * 16 + er + r;
          if (OUT == 1) {
            Cf[(size_t)row * N + col] = acc[i][j][r] + bias[col];
          } else {
            Cb[(size_t)row * N + col] = f2u(acc[i][j][r]);
          }
        }
      }
    }
  }
}

// ---------------- flash attention ----------------
// Y2: (8192 x 4096) bf16, cols [0,2048)=Q (pre-scaled by 1/sqrt(Dh)), [2048,4096)=K.
// Vtg: [64 bh][128 dh][2048 t] bf16 (V transposed per head).
// Block: 4 waves x 16 q-rows = 64 q-rows. KV tile = 64. No block-wide barriers.
__global__ __launch_bounds__(256)
void attn_kernel(const unsigned short* __restrict__ Y2,
                 const unsigned short* __restrict__ Vtg,
                 unsigned short* __restrict__ att) {
  __shared__ unsigned short Pl[4][16 * 72];  // per-wave P tile, padded stride 72

  const int t = threadIdx.x;
  const int w = t >> 6;
  const int l = t & 63;
  const int bid = blockIdx.x;
  const int qt = bid & 31;   // q-tile fastest: same (b,h) K/V hot in cache
  const int bh = bid >> 5;
  const int b = bh >> 4;
  const int h = bh & 15;

  const size_t ybase = (size_t)b * 2048 * 4096 + (size_t)h * 128;
  const unsigned short* Qp = Y2 + ybase;
  const unsigned short* Kp = Y2 + ybase + 2048;
  const unsigned short* Vp = Vtg + (size_t)bh * 128 * 2048;

  const int fr = l & 15;
  const int fkb = l >> 4;

  const int qrow = qt * 64 + w * 16 + fr;
  bf16x8 qf[4];
#pragma unroll
  for (int kk = 0; kk < 4; kk++)
    qf[kk] = *reinterpret_cast<const bf16x8*>(
        &Qp[(size_t)qrow * 4096 + kk * 32 + fkb * 8]);

  floatx4 oacc[8];
#pragma unroll
  for (int nt = 0; nt < 8; nt++) oacc[nt] = (floatx4){0.f, 0.f, 0.f, 0.f};
  float mrun[4], lrun[4];
#pragma unroll
  for (int r = 0; r < 4; r++) {
    mrun[r] = -INFINITY;
    lrun[r] = 0.f;
  }

  unsigned short* Pw = &Pl[w][0];

  for (int kv = 0; kv < 2048; kv += 64) {
    // ---- S = Q K^T : 16 q-rows x 64 kv-cols (scores pre-scaled via wq) ----
    floatx4 sacc[4];
#pragma unroll
    for (int nt = 0; nt < 4; nt++) sacc[nt] = (floatx4){0.f, 0.f, 0.f, 0.f};
#pragma unroll
    for (int nt = 0; nt < 4; nt++) {
      const unsigned short* krow =
          Kp + (size_t)(kv + nt * 16 + fr) * 4096 + fkb * 8;
#pragma unroll
      for (int kk = 0; kk < 4; kk++) {
        bf16x8 kf = *reinterpret_cast<const bf16x8*>(krow + kk * 32);
        sacc[nt] = mfma16(qf[kk], kf, sacc[nt]);
      }
    }

    // ---- online softmax with defer-max (THR=8); q-row = fkb*4+r ----
#pragma unroll
    for (int r = 0; r < 4; r++) {
      float s0 = sacc[0][r], s1 = sacc[1][r], s2 = sacc[2][r], s3 = sacc[3][r];
      float mx = fmaxf(fmaxf(s0, s1), fmaxf(s2, s3));
      mx = fmaxf(mx, __shfl_xor(mx, 1));
      mx = fmaxf(mx, __shfl_xor(mx, 2));
      mx = fmaxf(mx, __shfl_xor(mx, 4));
      mx = fmaxf(mx, __shfl_xor(mx, 8));
      if (mx > mrun[r] + 8.0f) {  // uniform within 16-lane group
        float alpha = __expf(mrun[r] - mx);
        mrun[r] = mx;
        lrun[r] *= alpha;
#pragma unroll
        for (int nt = 0; nt < 8; nt++) oacc[nt][r] *= alpha;
      }
      const float m = mrun[r];
      float p0 = __expf(s0 - m);
      float p1 = __expf(s1 - m);
      float p2 = __expf(s2 - m);
      float p3 = __expf(s3 - m);
      float ps = (p0 + p1) + (p2 + p3);
      ps += __shfl_xor(ps, 1);
      ps += __shfl_xor(ps, 2);
      ps += __shfl_xor(ps, 4);
      ps += __shfl_xor(ps, 8);
      lrun[r] += ps;
      const int pr = fkb * 4 + r;
      Pw[pr * 72 + fr] = f2u(p0);
      Pw[pr * 72 + 16 + fr] = f2u(p1);
      Pw[pr * 72 + 32 + fr] = f2u(p2);
      Pw[pr * 72 + 48 + fr] = f2u(p3);
    }

    // ---- PV: out(16x128) += P(16x64) @ V(64x128); V^T rows direct from global ----
    bf16x8 pf0 = *reinterpret_cast<const bf16x8*>(Pw + fr * 72 + fkb * 8);
    bf16x8 pf1 = *reinterpret_cast<const bf16x8*>(Pw + fr * 72 + 32 + fkb * 8);
#pragma unroll
    for (int nt = 0; nt < 8; nt++) {
      const unsigned short* vrow =
          Vp + (size_t)(nt * 16 + fr) * 2048 + kv + fkb * 8;
      bf16x8 vf0 = *reinterpret_cast<const bf16x8*>(vrow);
      bf16x8 vf1 = *reinterpret_cast<const bf16x8*>(vrow + 32);
      oacc[nt] = mfma16(pf0, vf0, oacc[nt]);
      oacc[nt] = mfma16(pf1, vf1, oacc[nt]);
    }
  }

  // ---- epilogue ----
#pragma unroll
  for (int r = 0; r < 4; r++) {
    const float inv = 1.0f / lrun[r];
    const int row = qt * 64 + w * 16 + fkb * 4 + r;
    unsigned short* op = att + ((size_t)b * 2048 + row) * 2048 + h * 128 + fr;
#pragma unroll
    for (int nt = 0; nt < 8; nt++) op[nt * 16] = f2u(oacc[nt][r] * inv);
  }
}

// ---------------- launch ----------------
extern "C" void kernel_launch(void* const* d_in, const int* in_sizes, int n_in,
                              void* d_out, int out_size, void* d_ws, size_t ws_size,
                              hipStream_t stream) {
  const float* x = (const float*)d_in[0];
  const float* wq = (const float*)d_in[1];
  const float* wk = (const float*)d_in[2];
  const float* wv = (const float*)d_in[3];
  const float* wo = (const float*)d_in[4];
  const float* bo = (const float*)d_in[5];

  unsigned short* ws = (unsigned short*)d_ws;
  unsigned short* x16 = ws;                      // 16,777,216
  unsigned short* wqkv16 = x16 + 16777216;       // 12,582,912
  unsigned short* wo16 = wqkv16 + 12582912;      // 4,194,304
  unsigned short* Y2 = wo16 + 4194304;           // 33,554,432 (8192 x 4096, Q|K)
  unsigned short* Vtg = Y2 + 33554432;           // 16,777,216 (64 x 128 x 2048)
  unsigned short* att16 = Vtg + 16777216;        // 16,777,216
  // total 100,663,296 ushorts = 201.3 MB (same footprint as R1)

  const float sscale = 0.08838834764831845f;  // 1/sqrt(128), folded into wq

  castk<<<16384, 256, 0, stream>>>(x, x16, 4194304, 1.0f);
  castk<<<4096, 256, 0, stream>>>(wq, wqkv16, 1048576, sscale);
  castk<<<4096, 256, 0, stream>>>(wk, wqkv16 + 4194304, 1048576, 1.0f);
  castk<<<4096, 256, 0, stream>>>(wv, wqkv16 + 8388608, 1048576, 1.0f);
  castk<<<4096, 256, 0, stream>>>(wo, wo16, 1048576, 1.0f);

  // Q,K projections -> Y2 (row-major)
  dim3 gqk(32, 64);
  gemm_bt<0><<<gqk, 256, 0, stream>>>(x16, wqkv16, Y2, nullptr, nullptr,
                                      8192, 4096, 2048);
  // V projection -> Vtg (transposed per head)
  dim3 gv(16, 64);
  gemm_bt<2><<<gv, 256, 0, stream>>>(x16, wqkv16 + 8388608, Vtg, nullptr,
                                     nullptr, 8192, 2048, 2048);

  attn_kernel<<<2048, 256, 0, stream>>>(Y2, Vtg, att16);

  dim3 go(16, 64);
  gemm_bt<1><<<go, 256, 0, stream>>>(att16, wo16, nullptr, (float*)d_out, bo,
                                     8192, 2048, 2048);
}

// Round 3
// 1111.093 us; speedup vs baseline: 1.1803x; 1.1803x over previous
//
#include <hip/hip_runtime.h>
#include <hip/hip_bf16.h>
#include <math.h>

typedef __attribute__((ext_vector_type(8))) __bf16 bf16x8;
typedef __attribute__((ext_vector_type(4))) float floatx4;

__device__ inline unsigned short f2u(float f) {
  __hip_bfloat16 h = __float2bfloat16(f);
  unsigned short u;
  __builtin_memcpy(&u, &h, 2);
  return u;
}

__device__ inline floatx4 mfma16(bf16x8 a, bf16x8 b, floatx4 c) {
  return __builtin_amdgcn_mfma_f32_16x16x32_bf16(a, b, c, 0, 0, 0);
}

__device__ inline void gload_lds16(const unsigned short* g, unsigned short* l) {
  __builtin_amdgcn_global_load_lds(
      (__attribute__((address_space(1))) void*)g,
      (__attribute__((address_space(3))) void*)l,
      16, 0, 0);
}

// ---------------- cast fp32 -> bf16 (vectorized, optional scale) ----------------
__global__ __launch_bounds__(256) void castk(const float* __restrict__ in,
                                             unsigned short* __restrict__ out,
                                             int n4, float scale) {
  int i = blockIdx.x * 256 + threadIdx.x;
  if (i >= n4) return;
  const float4 v = reinterpret_cast<const float4*>(in)[i];
  ushort4 o;
  o.x = f2u(v.x * scale);
  o.y = f2u(v.y * scale);
  o.z = f2u(v.z * scale);
  o.w = f2u(v.w * scale);
  reinterpret_cast<ushort4*>(out)[i] = o;
}

// ---------------- GEMM: C[m,n] = sum_k A[m,k] * B[n,k]  (both row-major, K inner) ----
// 128x128 tile, BK=32, 4 waves (2x2), 4x4 16x16x32 bf16 MFMA frags per wave.
// OUT: 0 = bf16 row-major, 1 = f32 row-major + bias, 2 = bf16 transposed-per-head
//      (Vtg[((b*16+hv)*128+dh)*2048 + t], for the V projection)
template <int OUT>
__global__ __launch_bounds__(256)
void gemm_bt(const unsigned short* __restrict__ A,
             const unsigned short* __restrict__ B,
             unsigned short* __restrict__ Cb,
             float* __restrict__ Cf,
             const float* __restrict__ bias,
             int M, int N, int K) {
  __shared__ unsigned short Asm_[128 * 32];
  __shared__ unsigned short Bsm_[128 * 32];
  const int t = threadIdx.x;
  const int w = t >> 6;
  const int l = t & 63;
  const int m0 = blockIdx.y * 128;
  const int n0 = blockIdx.x * 128;
  const int wm = w >> 1, wn = w & 1;

  const int srow = l >> 2;
  const int scol = (l & 3) * 8;
  const unsigned short* gA = A + (size_t)(m0 + w * 32 + srow) * K + scol;
  const unsigned short* gB = B + (size_t)(n0 + w * 32 + srow) * K + scol;
  unsigned short* lA = &Asm_[w * 1024];
  unsigned short* lB = &Bsm_[w * 1024];

  floatx4 acc[4][4];
#pragma unroll
  for (int i = 0; i < 4; i++)
#pragma unroll
    for (int j = 0; j < 4; j++) acc[i][j] = (floatx4){0.f, 0.f, 0.f, 0.f};

  const int fr = l & 15;
  const int fk = (l >> 4) * 8;

  for (int k0 = 0; k0 < K; k0 += 32) {
    gload_lds16(gA + k0, lA);
    gload_lds16(gA + (size_t)16 * K + k0, lA + 512);
    gload_lds16(gB + k0, lB);
    gload_lds16(gB + (size_t)16 * K + k0, lB + 512);
    __syncthreads();

    bf16x8 af[4], bfr[4];
#pragma unroll
    for (int i = 0; i < 4; i++)
      af[i] = *reinterpret_cast<const bf16x8*>(&Asm_[(wm * 64 + i * 16 + fr) * 32 + fk]);
#pragma unroll
    for (int j = 0; j < 4; j++)
      bfr[j] = *reinterpret_cast<const bf16x8*>(&Bsm_[(wn * 64 + j * 16 + fr) * 32 + fk]);
#pragma unroll
    for (int i = 0; i < 4; i++)
#pragma unroll
      for (int j = 0; j < 4; j++) acc[i][j] = mfma16(af[i], bfr[j], acc[i][j]);
    __syncthreads();
  }

  const int er = (l >> 4) * 4;
  const int ec = l & 15;
#pragma unroll
  for (int i = 0; i < 4; i++) {
#pragma unroll
    for (int j = 0; j < 4; j++) {
      const int col = n0 + wn * 64 + j * 16 + ec;
      if (OUT == 2) {
        const int hv = col >> 7, dh = col & 127;
        const int row0 = m0 + wm * 64 + i * 16 + er;
        const int bb = row0 >> 11;
        const int t0 = row0 & 2047;
        unsigned short* vp =
            Cb + (((size_t)(bb * 16 + hv)) * 128 + dh) * 2048 + t0;
#pragma unroll
        for (int r = 0; r < 4; r++) vp[r] = f2u(acc[i][j][r]);
      } else {
#pragma unroll
        for (int r = 0; r < 4; r++) {
          const int row = m0 + wm * 64 + i * 16 + er + r;
          if (OUT == 1) {
            Cf[(size_t)row * N + col] = acc[i][j][r] + bias[col];
          } else {
            Cb[(size_t)row * N + col] = f2u(acc[i][j][r]);
          }
        }
      }
    }
  }
}

// ---------------- flash attention ----------------
// Y2: (8192 x 4096) bf16, cols [0,2048)=Q (pre-scaled by 1/sqrt(Dh)), [2048,4096)=K.
// Vtg: [64 bh][128 dh][2048 t] bf16 (V transposed per head).
// Block: 4 waves x 16 q-rows = 64 q-rows. KV tile = 64.
// V^T tile double-buffered in LDS, XOR-swizzled via pre-swizzled global source
// (global_load_lds linear dest). One barrier per iter; staging overlaps compute.
__global__ __launch_bounds__(256)
void attn_kernel(const unsigned short* __restrict__ Y2,
                 const unsigned short* __restrict__ Vtg,
                 unsigned short* __restrict__ att) {
  __shared__ unsigned short Vt[2][128 * 64];  // 32 KB: [dh][kv] swizzled
  __shared__ unsigned short Pl[4][16 * 72];   // per-wave P, padded stride 72

  const int t = threadIdx.x;
  const int w = t >> 6;
  const int l = t & 63;
  const int bid = blockIdx.x;
  const int bh = bid & 63;  // bh-fastest: compulsory-only HBM traffic (R1 behavior)
  const int qt = bid >> 6;
  const int b = bh >> 4;
  const int h = bh & 15;

  const size_t ybase = (size_t)b * 2048 * 4096 + (size_t)h * 128;
  const unsigned short* Qp = Y2 + ybase;
  const unsigned short* Kp = Y2 + ybase + 2048;
  const unsigned short* Vp = Vtg + (size_t)bh * 128 * 2048;

  const int fr = l & 15;
  const int fkb = l >> 4;

  // ---- V staging geometry: lane l covers LDS row (w*8 + c*32 + l>>3), slot l&7.
  // Stored slot s holds logical slot s ^ (row&7)  (involution) -> source addr swizzled.
  const int sr = l >> 3;              // row within 8-row group = row & 7
  const int ssw = (l & 7) ^ sr;       // logical slot for this lane's dest slot
  const unsigned short* Vsrc0 = Vp + (size_t)(w * 8 + sr) * 2048 + ssw * 8;

  const int qrow = qt * 64 + w * 16 + fr;
  bf16x8 qf[4];
#pragma unroll
  for (int kk = 0; kk < 4; kk++)
    qf[kk] = *reinterpret_cast<const bf16x8*>(
        &Qp[(size_t)qrow * 4096 + kk * 32 + fkb * 8]);

  floatx4 oacc[8];
#pragma unroll
  for (int nt = 0; nt < 8; nt++) oacc[nt] = (floatx4){0.f, 0.f, 0.f, 0.f};
  float mrun[4], lrun[4];
#pragma unroll
  for (int r = 0; r < 4; r++) {
    mrun[r] = -INFINITY;
    lrun[r] = 0.f;
  }

  unsigned short* Pw = &Pl[w][0];
  const int psw = fr & 7;  // read-side swizzle key for V

  // prologue: stage tile 0 into buf 0
#pragma unroll
  for (int c = 0; c < 4; c++)
    gload_lds16(Vsrc0 + (size_t)c * 32 * 2048, &Vt[0][(w * 64 + c * 256) * 8]);
  __syncthreads();  // drains vmcnt -> V(0) ready

  int cur = 0;
  for (int kv = 0; kv < 2048; kv += 64) {
    // ---- issue next V tile's stage into the other buffer (overlaps compute) ----
    if (kv + 64 < 2048) {
#pragma unroll
      for (int c = 0; c < 4; c++)
        gload_lds16(Vsrc0 + (size_t)c * 32 * 2048 + (kv + 64),
                    &Vt[cur ^ 1][(w * 64 + c * 256) * 8]);
    }

    // ---- S = Q K^T : 16 q-rows x 64 kv-cols (pre-scaled via wq) ----
    floatx4 sacc[4];
#pragma unroll
    for (int nt = 0; nt < 4; nt++) sacc[nt] = (floatx4){0.f, 0.f, 0.f, 0.f};
#pragma unroll
    for (int nt = 0; nt < 4; nt++) {
      const unsigned short* krow =
          Kp + (size_t)(kv + nt * 16 + fr) * 4096 + fkb * 8;
#pragma unroll
      for (int kk = 0; kk < 4; kk++) {
        bf16x8 kf = *reinterpret_cast<const bf16x8*>(krow + kk * 32);
        sacc[nt] = mfma16(qf[kk], kf, sacc[nt]);
      }
    }

    // ---- online softmax with defer-max (THR=8); q-row = fkb*4+r ----
#pragma unroll
    for (int r = 0; r < 4; r++) {
      float s0 = sacc[0][r], s1 = sacc[1][r], s2 = sacc[2][r], s3 = sacc[3][r];
      float mx = fmaxf(fmaxf(s0, s1), fmaxf(s2, s3));
      mx = fmaxf(mx, __shfl_xor(mx, 1));
      mx = fmaxf(mx, __shfl_xor(mx, 2));
      mx = fmaxf(mx, __shfl_xor(mx, 4));
      mx = fmaxf(mx, __shfl_xor(mx, 8));
      if (mx > mrun[r] + 8.0f) {
        float alpha = __expf(mrun[r] - mx);
        mrun[r] = mx;
        lrun[r] *= alpha;
#pragma unroll
        for (int nt = 0; nt < 8; nt++) oacc[nt][r] *= alpha;
      }
      const float m = mrun[r];
      float p0 = __expf(s0 - m);
      float p1 = __expf(s1 - m);
      float p2 = __expf(s2 - m);
      float p3 = __expf(s3 - m);
      float ps = (p0 + p1) + (p2 + p3);
      ps += __shfl_xor(ps, 1);
      ps += __shfl_xor(ps, 2);
      ps += __shfl_xor(ps, 4);
      ps += __shfl_xor(ps, 8);
      lrun[r] += ps;
      const int pr = fkb * 4 + r;
      Pw[pr * 72 + fr] = f2u(p0);
      Pw[pr * 72 + 16 + fr] = f2u(p1);
      Pw[pr * 72 + 32 + fr] = f2u(p2);
      Pw[pr * 72 + 48 + fr] = f2u(p3);
    }

    // ---- PV: out(16x128) += P(16x64) @ V(64x128); V^T from swizzled LDS ----
    bf16x8 pf0 = *reinterpret_cast<const bf16x8*>(Pw + fr * 72 + fkb * 8);
    bf16x8 pf1 = *reinterpret_cast<const bf16x8*>(Pw + fr * 72 + 32 + fkb * 8);
    const unsigned short* vb = &Vt[cur][0];
#pragma unroll
    for (int nt = 0; nt < 8; nt++) {
      const unsigned short* vr0 = vb + (nt * 16 + fr) * 64;
      bf16x8 vf0 = *reinterpret_cast<const bf16x8*>(vr0 + ((fkb ^ psw) * 8));
      bf16x8 vf1 = *reinterpret_cast<const bf16x8*>(vr0 + (((fkb + 4) ^ psw) * 8));
      oacc[nt] = mfma16(pf0, vf0, oacc[nt]);
      oacc[nt] = mfma16(pf1, vf1, oacc[nt]);
    }

    __syncthreads();  // drains vmcnt (next V landed); all reads of Vt[cur] done
    cur ^= 1;
  }

  // ---- epilogue ----
#pragma unroll
  for (int r = 0; r < 4; r++) {
    const float inv = 1.0f / lrun[r];
    const int row = qt * 64 + w * 16 + fkb * 4 + r;
    unsigned short* op = att + ((size_t)b * 2048 + row) * 2048 + h * 128 + fr;
#pragma unroll
    for (int nt = 0; nt < 8; nt++) op[nt * 16] = f2u(oacc[nt][r] * inv);
  }
}

// ---------------- launch ----------------
extern "C" void kernel_launch(void* const* d_in, const int* in_sizes, int n_in,
                              void* d_out, int out_size, void* d_ws, size_t ws_size,
                              hipStream_t stream) {
  const float* x = (const float*)d_in[0];
  const float* wq = (const float*)d_in[1];
  const float* wk = (const float*)d_in[2];
  const float* wv = (const float*)d_in[3];
  const float* wo = (const float*)d_in[4];
  const float* bo = (const float*)d_in[5];

  unsigned short* ws = (unsigned short*)d_ws;
  unsigned short* x16 = ws;                      // 16,777,216
  unsigned short* wqkv16 = x16 + 16777216;       // 12,582,912
  unsigned short* wo16 = wqkv16 + 12582912;      // 4,194,304
  unsigned short* Y2 = wo16 + 4194304;           // 33,554,432 (8192 x 4096, Q|K)
  unsigned short* Vtg = Y2 + 33554432;           // 16,777,216 (64 x 128 x 2048)
  unsigned short* att16 = Vtg + 16777216;        // 16,777,216
  // total 100,663,296 ushorts = 201.3 MB

  const float sscale = 0.08838834764831845f;  // 1/sqrt(128), folded into wq

  castk<<<16384, 256, 0, stream>>>(x, x16, 4194304, 1.0f);
  castk<<<4096, 256, 0, stream>>>(wq, wqkv16, 1048576, sscale);
  castk<<<4096, 256, 0, stream>>>(wk, wqkv16 + 4194304, 1048576, 1.0f);
  castk<<<4096, 256, 0, stream>>>(wv, wqkv16 + 8388608, 1048576, 1.0f);
  castk<<<4096, 256, 0, stream>>>(wo, wo16, 1048576, 1.0f);

  // Q,K projections -> Y2 (row-major)
  dim3 gqk(32, 64);
  gemm_bt<0><<<gqk, 256, 0, stream>>>(x16, wqkv16, Y2, nullptr, nullptr,
                                      8192, 4096, 2048);
  // V projection -> Vtg (transposed per head)
  dim3 gv(16, 64);
  gemm_bt<2><<<gv, 256, 0, stream>>>(x16, wqkv16 + 8388608, Vtg, nullptr,
                                     nullptr, 8192, 2048, 2048);

  attn_kernel<<<2048, 256, 0, stream>>>(Y2, Vtg, att16);

  dim3 go(16, 64);
  gemm_bt<1><<<go, 256, 0, stream>>>(att16, wo16, nullptr, (float*)d_out, bo,
                                     8192, 2048, 2048);
}

// Round 4
// 681.965 us; speedup vs baseline: 1.9230x; 1.6293x over previous
//
#include <hip/hip_runtime.h>
#include <hip/hip_bf16.h>
#include <math.h>

typedef __attribute__((ext_vector_type(8))) __bf16 bf16x8;
typedef __attribute__((ext_vector_type(4))) float floatx4;

__device__ inline unsigned short f2u(float f) {
  __hip_bfloat16 h = __float2bfloat16(f);
  unsigned short u;
  __builtin_memcpy(&u, &h, 2);
  return u;
}

__device__ inline floatx4 mfma16(bf16x8 a, bf16x8 b, floatx4 c) {
  return __builtin_amdgcn_mfma_f32_16x16x32_bf16(a, b, c, 0, 0, 0);
}

__device__ inline void gload_lds16(const unsigned short* g, unsigned short* l) {
  __builtin_amdgcn_global_load_lds(
      (__attribute__((address_space(1))) void*)g,
      (__attribute__((address_space(3))) void*)l,
      16, 0, 0);
}

// ---------------- cast fp32 -> bf16 (vectorized, optional scale) ----------------
__global__ __launch_bounds__(256) void castk(const float* __restrict__ in,
                                             unsigned short* __restrict__ out,
                                             int n4, float scale) {
  int i = blockIdx.x * 256 + threadIdx.x;
  if (i >= n4) return;
  const float4 v = reinterpret_cast<const float4*>(in)[i];
  ushort4 o;
  o.x = f2u(v.x * scale);
  o.y = f2u(v.y * scale);
  o.z = f2u(v.z * scale);
  o.w = f2u(v.w * scale);
  reinterpret_cast<ushort4*>(out)[i] = o;
}

// ---------------- GEMM: C[m,n] = sum_k A[m,k] * B[n,k] ----
template <int OUT>
__global__ __launch_bounds__(256)
void gemm_bt(const unsigned short* __restrict__ A,
             const unsigned short* __restrict__ B,
             unsigned short* __restrict__ Cb,
             float* __restrict__ Cf,
             const float* __restrict__ bias,
             int M, int N, int K) {
  __shared__ unsigned short Asm_[128 * 32];
  __shared__ unsigned short Bsm_[128 * 32];
  const int t = threadIdx.x;
  const int w = t >> 6;
  const int l = t & 63;
  const int m0 = blockIdx.y * 128;
  const int n0 = blockIdx.x * 128;
  const int wm = w >> 1, wn = w & 1;

  const int srow = l >> 2;
  const int scol = (l & 3) * 8;
  const unsigned short* gA = A + (size_t)(m0 + w * 32 + srow) * K + scol;
  const unsigned short* gB = B + (size_t)(n0 + w * 32 + srow) * K + scol;
  unsigned short* lA = &Asm_[w * 1024];
  unsigned short* lB = &Bsm_[w * 1024];

  floatx4 acc[4][4];
#pragma unroll
  for (int i = 0; i < 4; i++)
#pragma unroll
    for (int j = 0; j < 4; j++) acc[i][j] = (floatx4){0.f, 0.f, 0.f, 0.f};

  const int fr = l & 15;
  const int fk = (l >> 4) * 8;

  for (int k0 = 0; k0 < K; k0 += 32) {
    gload_lds16(gA + k0, lA);
    gload_lds16(gA + (size_t)16 * K + k0, lA + 512);
    gload_lds16(gB + k0, lB);
    gload_lds16(gB + (size_t)16 * K + k0, lB + 512);
    __syncthreads();

    bf16x8 af[4], bfr[4];
#pragma unroll
    for (int i = 0; i < 4; i++)
      af[i] = *reinterpret_cast<const bf16x8*>(&Asm_[(wm * 64 + i * 16 + fr) * 32 + fk]);
#pragma unroll
    for (int j = 0; j < 4; j++)
      bfr[j] = *reinterpret_cast<const bf16x8*>(&Bsm_[(wn * 64 + j * 16 + fr) * 32 + fk]);
#pragma unroll
    for (int i = 0; i < 4; i++)
#pragma unroll
      for (int j = 0; j < 4; j++) acc[i][j] = mfma16(af[i], bfr[j], acc[i][j]);
    __syncthreads();
  }

  const int er = (l >> 4) * 4;
  const int ec = l & 15;
#pragma unroll
  for (int i = 0; i < 4; i++) {
#pragma unroll
    for (int j = 0; j < 4; j++) {
      const int col = n0 + wn * 64 + j * 16 + ec;
      if (OUT == 2) {
        const int hv = col >> 7, dh = col & 127;
        const int row0 = m0 + wm * 64 + i * 16 + er;
        const int bb = row0 >> 11;
        const int t0 = row0 & 2047;
        unsigned short* vp =
            Cb + (((size_t)(bb * 16 + hv)) * 128 + dh) * 2048 + t0;
#pragma unroll
        for (int r = 0; r < 4; r++) vp[r] = f2u(acc[i][j][r]);
      } else {
#pragma unroll
        for (int r = 0; r < 4; r++) {
          const int row = m0 + wm * 64 + i * 16 + er + r;
          if (OUT == 1) {
            Cf[(size_t)row * N + col] = acc[i][j][r] + bias[col];
          } else {
            Cb[(size_t)row * N + col] = f2u(acc[i][j][r]);
          }
        }
      }
    }
  }
}

// ---------------- flash attention ----------------
// Y2: (8192 x 4096) bf16, cols [0,2048)=Q (pre-scaled), [2048,4096)=K.
// Vtg: [64 bh][128 dh][2048 t] bf16 (V transposed per head).
// Block: 4 waves x 32 q-rows = 128 q-rows. KV tile = 64.
// K double-buffered in LDS (XOR-swizzled via pre-swizzled global source),
// V single-buffered (staged at iter top, consumed post-barrier). 2 barriers/iter.
__global__ __launch_bounds__(256, 2)
void attn_kernel(const unsigned short* __restrict__ Y2,
                 const unsigned short* __restrict__ Vtg,
                 unsigned short* __restrict__ att) {
  __shared__ unsigned short Kt[2][64 * 128];  // 2 x 16 KB, [kvrow][dh] swizzled
  __shared__ unsigned short Vt[128 * 64];     // 16 KB, [dh][kv] swizzled
  __shared__ unsigned short Pl[4][32 * 72];   // per-wave P, padded stride 72

  const int t = threadIdx.x;
  const int w = t >> 6;
  const int l = t & 63;
  const int bid = blockIdx.x;
  const int bh = bid & 63;
  const int qt = bid >> 6;  // 0..15, 128 q-rows each
  const int b = bh >> 4;
  const int h = bh & 15;

  const size_t ybase = (size_t)b * 2048 * 4096 + (size_t)h * 128;
  const unsigned short* Qp = Y2 + ybase;
  const unsigned short* Kp = Y2 + ybase + 2048;
  const unsigned short* Vp = Vtg + (size_t)bh * 128 * 2048;

  const int fr = l & 15;
  const int fkb = l >> 4;
  const int key = fr & 7;  // read-side swizzle key (row & 7)

  // K staging: block-wide, call c covers rows c*16 + (t>>4), dest slot t&15 (of 16).
  // Stored slot s holds logical slot s ^ (row&7); row&7 = (t>>4)&7.
  const int ksr = t >> 4;
  const int ksl = (t & 15) ^ (ksr & 7);
  const unsigned short* Ksrc = Kp + (size_t)ksr * 4096 + ksl * 8;

  // V staging: call c covers rows c*32 + (t>>3), dest slot t&7 (of 8).
  const int vsr = t >> 3;
  const int vsl = (t & 7) ^ (vsr & 7);
  const unsigned short* Vsrc = Vp + (size_t)vsr * 2048 + vsl * 8;

  // Q fragments: rows qt*128 + w*32 + i*16 + fr
  bf16x8 qf[2][4];
#pragma unroll
  for (int i = 0; i < 2; i++)
#pragma unroll
    for (int kk = 0; kk < 4; kk++)
      qf[i][kk] = *reinterpret_cast<const bf16x8*>(
          &Qp[(size_t)(qt * 128 + w * 32 + i * 16 + fr) * 4096 + kk * 32 + fkb * 8]);

  floatx4 oacc[2][8];
#pragma unroll
  for (int i = 0; i < 2; i++)
#pragma unroll
    for (int nt = 0; nt < 8; nt++) oacc[i][nt] = (floatx4){0.f, 0.f, 0.f, 0.f};
  float mrun[2][4], lrun[2][4];
#pragma unroll
  for (int i = 0; i < 2; i++)
#pragma unroll
    for (int r = 0; r < 4; r++) {
      mrun[i][r] = -INFINITY;
      lrun[i][r] = 0.f;
    }

  unsigned short* Pw = &Pl[w][0];

  // prologue: stage K(0) into Kt[0]
#pragma unroll
  for (int c = 0; c < 4; c++)
    gload_lds16(Ksrc + (size_t)c * 16 * 4096, &Kt[0][c * 2048 + w * 512]);
  __syncthreads();

  int cur = 0;
  for (int kv = 0; kv < 2048; kv += 64) {
    // ---- stage V(kv) (prev barrier guaranteed all PV reads of Vt done) ----
#pragma unroll
    for (int c = 0; c < 4; c++)
      gload_lds16(Vsrc + (size_t)c * 32 * 2048 + kv, &Vt[c * 2048 + w * 512]);

    // ---- QK^T: 32 q-rows x 64 kv from Kt[cur] ----
    floatx4 sacc[2][4];
#pragma unroll
    for (int i = 0; i < 2; i++)
#pragma unroll
      for (int nt = 0; nt < 4; nt++) sacc[i][nt] = (floatx4){0.f, 0.f, 0.f, 0.f};
#pragma unroll
    for (int nt = 0; nt < 4; nt++) {
#pragma unroll
      for (int kk = 0; kk < 4; kk++) {
        bf16x8 kf = *reinterpret_cast<const bf16x8*>(
            &Kt[cur][((nt * 16 + fr) * 16 + ((kk * 4 + fkb) ^ key)) * 8]);
        sacc[0][nt] = mfma16(qf[0][kk], kf, sacc[0][nt]);
        sacc[1][nt] = mfma16(qf[1][kk], kf, sacc[1][nt]);
      }
    }

    // ---- online softmax with defer-max (THR=8); q-row-in-16 = fkb*4+r ----
#pragma unroll
    for (int i = 0; i < 2; i++) {
#pragma unroll
      for (int r = 0; r < 4; r++) {
        float s0 = sacc[i][0][r], s1 = sacc[i][1][r];
        float s2 = sacc[i][2][r], s3 = sacc[i][3][r];
        float mx = fmaxf(fmaxf(s0, s1), fmaxf(s2, s3));
        mx = fmaxf(mx, __shfl_xor(mx, 1));
        mx = fmaxf(mx, __shfl_xor(mx, 2));
        mx = fmaxf(mx, __shfl_xor(mx, 4));
        mx = fmaxf(mx, __shfl_xor(mx, 8));
        if (mx > mrun[i][r] + 8.0f) {
          float alpha = __expf(mrun[i][r] - mx);
          mrun[i][r] = mx;
          lrun[i][r] *= alpha;
#pragma unroll
          for (int nt = 0; nt < 8; nt++) oacc[i][nt][r] *= alpha;
        }
        const float m = mrun[i][r];
        float p0 = __expf(s0 - m);
        float p1 = __expf(s1 - m);
        float p2 = __expf(s2 - m);
        float p3 = __expf(s3 - m);
        float ps = (p0 + p1) + (p2 + p3);
        ps += __shfl_xor(ps, 1);
        ps += __shfl_xor(ps, 2);
        ps += __shfl_xor(ps, 4);
        ps += __shfl_xor(ps, 8);
        lrun[i][r] += ps;
        const int pr = i * 16 + fkb * 4 + r;
        Pw[pr * 72 + fr] = f2u(p0);
        Pw[pr * 72 + 16 + fr] = f2u(p1);
        Pw[pr * 72 + 32 + fr] = f2u(p2);
        Pw[pr * 72 + 48 + fr] = f2u(p3);
      }
    }

    __syncthreads();  // V(kv) landed; Kt[cur^1] free (its readers finished last iter)

    // ---- stage K(kv+64) into Kt[cur^1]; latency hides under PV ----
    if (kv + 64 < 2048) {
#pragma unroll
      for (int c = 0; c < 4; c++)
        gload_lds16(Ksrc + (size_t)(kv + 64 + c * 16) * 4096,
                    &Kt[cur ^ 1][c * 2048 + w * 512]);
    }

    // ---- PV: out(32x128) += P(32x64) @ V(64x128) ----
    bf16x8 pf[2][2];
#pragma unroll
    for (int i = 0; i < 2; i++) {
      pf[i][0] = *reinterpret_cast<const bf16x8*>(&Pw[(i * 16 + fr) * 72 + fkb * 8]);
      pf[i][1] = *reinterpret_cast<const bf16x8*>(&Pw[(i * 16 + fr) * 72 + 32 + fkb * 8]);
    }
#pragma unroll
    for (int nt = 0; nt < 8; nt++) {
      const unsigned short* vr = &Vt[(nt * 16 + fr) * 64];
      bf16x8 vf0 = *reinterpret_cast<const bf16x8*>(vr + (fkb ^ key) * 8);
      bf16x8 vf1 = *reinterpret_cast<const bf16x8*>(vr + ((fkb + 4) ^ key) * 8);
#pragma unroll
      for (int i = 0; i < 2; i++) {
        oacc[i][nt] = mfma16(pf[i][0], vf0, oacc[i][nt]);
        oacc[i][nt] = mfma16(pf[i][1], vf1, oacc[i][nt]);
      }
    }

    __syncthreads();  // all waves done Vt/Kt[cur] reads; K(kv+64) drained
    cur ^= 1;
  }

  // ---- epilogue ----
#pragma unroll
  for (int i = 0; i < 2; i++) {
#pragma unroll
    for (int r = 0; r < 4; r++) {
      const float inv = 1.0f / lrun[i][r];
      const int row = qt * 128 + w * 32 + i * 16 + fkb * 4 + r;
      unsigned short* op = att + ((size_t)b * 2048 + row) * 2048 + h * 128 + fr;
#pragma unroll
      for (int nt = 0; nt < 8; nt++) op[nt * 16] = f2u(oacc[i][nt][r] * inv);
    }
  }
}

// ---------------- launch ----------------
extern "C" void kernel_launch(void* const* d_in, const int* in_sizes, int n_in,
                              void* d_out, int out_size, void* d_ws, size_t ws_size,
                              hipStream_t stream) {
  const float* x = (const float*)d_in[0];
  const float* wq = (const float*)d_in[1];
  const float* wk = (const float*)d_in[2];
  const float* wv = (const float*)d_in[3];
  const float* wo = (const float*)d_in[4];
  const float* bo = (const float*)d_in[5];

  unsigned short* ws = (unsigned short*)d_ws;
  unsigned short* x16 = ws;                      // 16,777,216
  unsigned short* wqkv16 = x16 + 16777216;       // 12,582,912
  unsigned short* wo16 = wqkv16 + 12582912;      // 4,194,304
  unsigned short* Y2 = wo16 + 4194304;           // 33,554,432 (8192 x 4096, Q|K)
  unsigned short* Vtg = Y2 + 33554432;           // 16,777,216 (64 x 128 x 2048)
  unsigned short* att16 = Vtg + 16777216;        // 16,777,216
  // total 100,663,296 ushorts = 201.3 MB

  const float sscale = 0.08838834764831845f;  // 1/sqrt(128), folded into wq

  castk<<<16384, 256, 0, stream>>>(x, x16, 4194304, 1.0f);
  castk<<<4096, 256, 0, stream>>>(wq, wqkv16, 1048576, sscale);
  castk<<<4096, 256, 0, stream>>>(wk, wqkv16 + 4194304, 1048576, 1.0f);
  castk<<<4096, 256, 0, stream>>>(wv, wqkv16 + 8388608, 1048576, 1.0f);
  castk<<<4096, 256, 0, stream>>>(wo, wo16, 1048576, 1.0f);

  // Q,K projections -> Y2 (row-major)
  dim3 gqk(32, 64);
  gemm_bt<0><<<gqk, 256, 0, stream>>>(x16, wqkv16, Y2, nullptr, nullptr,
                                      8192, 4096, 2048);
  // V projection -> Vtg (transposed per head)
  dim3 gv(16, 64);
  gemm_bt<2><<<gv, 256, 0, stream>>>(x16, wqkv16 + 8388608, Vtg, nullptr,
                                     nullptr, 8192, 2048, 2048);

  attn_kernel<<<1024, 256, 0, stream>>>(Y2, Vtg, att16);

  dim3 go(16, 64);
  gemm_bt<1><<<go, 256, 0, stream>>>(att16, wo16, nullptr, (float*)d_out, bo,
                                     8192, 2048, 2048);
}